// Round 8
// baseline (12.093 us; speedup 1.0000x reference)
//
#include <hip/hip_runtime.h>
#include <hip/hip_bf16.h>

// Problem: N=32, T=5, V=64, F=512, t_mid = 2
// xm = x[:, 2, :, :]                         (32, 64, 512)
// tmpS[n,i,j] = exp( sum_f |xm[n,i,f]-xm[n,j,f]| * a[f] )   (symmetric in i,j)
// colsum[n,i] = sum_k tmpS[n,k,i] == sum_k tmpS[n,i,k]  (symmetry -> row-local)
// S[n,i,j] = tmpS[n,i,j] / colsum[n,i]
//
// R8 = R7 structure (single global vj stream/thread, broadcast LDS vi/va,
// full unroll, XCD swizzle, __expf) with IB 4->8 and 512-thread blocks:
// each n-panel is re-read 8x instead of 16x -> L2 traffic 67->34 MB.

#define NN 32
#define TT 5
#define VV 64
#define FF 512
#define TMID 2
#define IB 8            // i-rows per block
#define RSTRIDE 65      // padded stride for red[] scatter

__global__ __launch_bounds__(512) void pairsim_kernel(
    const float* __restrict__ x, const float* __restrict__ a,
    float* __restrict__ out) {
  // Bijective XCD swizzle (256 blocks, 8 XCDs, 32 blocks/XCD):
  // 32 consecutive logical b (4 full n-panels) land on one XCD.
  const int b = ((blockIdx.x & 7) << 5) | (blockIdx.x >> 3);
  const int n = b >> 3;            // b / 8
  const int i0 = (b & 7) * IB;     // first i-row of this block
  const int t = threadIdx.x;       // 0 .. 511

  __shared__ float xi[IB * FF];        // 16 KB: rows i0..i0+7
  __shared__ float av[FF];             // 2 KB
  __shared__ float red[IB * RSTRIDE];  // ~2 KB

  const float* xm = x + ((size_t)n * TT + TMID) * (size_t)VV * FF;

  // Stage xi rows (contiguous 16 KB) + a into LDS, float4-coalesced.
  {
    const float4* src_xi = reinterpret_cast<const float4*>(xm + (size_t)i0 * FF);
    const float4* src_a  = reinterpret_cast<const float4*>(a);
    float4* dst_xi = reinterpret_cast<float4*>(xi);
    float4* dst_a  = reinterpret_cast<float4*>(av);
    for (int idx = t; idx < (IB * FF / 4) + (FF / 4); idx += 512) {
      if (idx < IB * FF / 4) dst_xi[idx] = src_xi[idx];
      else                   dst_a[idx - IB * FF / 4] = src_a[idx - IB * FF / 4];
    }
  }
  __syncthreads();

  const int j = t >> 3;            // 0..63
  const int part = t & 7;          // 0..7 f-partition
  const float* xj = xm + (size_t)j * FF;

  float acc[IB];
#pragma unroll
  for (int r = 0; r < IB; ++r) acc[r] = 0.f;

#pragma unroll
  for (int k = 0; k < 16; ++k) {
    const int f = k * 32 + part * 4;   // 8-lane part-group covers 128B contig
    float4 vj = *reinterpret_cast<const float4*>(xj + f);
    float4 va = *reinterpret_cast<const float4*>(av + f);
#pragma unroll
    for (int r = 0; r < IB; ++r) {
      float4 vi = *reinterpret_cast<const float4*>(xi + r * FF + f);
      acc[r] = fmaf(fabsf(vi.x - vj.x), va.x, acc[r]);
      acc[r] = fmaf(fabsf(vi.y - vj.y), va.y, acc[r]);
      acc[r] = fmaf(fabsf(vi.z - vj.z), va.z, acc[r]);
      acc[r] = fmaf(fabsf(vi.w - vj.w), va.w, acc[r]);
    }
  }

  // Fold the 8 f-partitions (xor butterfly within each 8-lane part-group).
#pragma unroll
  for (int r = 0; r < IB; ++r) {
    float v = acc[r];
    v += __shfl_xor(v, 1);
    v += __shfl_xor(v, 2);
    v += __shfl_xor(v, 4);
    acc[r] = v;
  }

  // Each thread writes exactly one exp value: row = part, column = j.
  {
    float pick = 0.f;
#pragma unroll
    for (int r = 0; r < IB; ++r)
      if (part == r) pick = acc[r];
    red[part * RSTRIDE + j] = __expf(pick);
  }
  __syncthreads();

  // 8 waves, one per i-row: butterfly row-sum, coalesced 256B row write.
  {
    const int w = t >> 6;          // 0..7 -> i-row
    const int lane = t & 63;       // j
    float v = red[w * RSTRIDE + lane];
    float s = v;
#pragma unroll
    for (int o = 1; o < 64; o <<= 1) s += __shfl_xor(s, o);
    out[(((size_t)n * VV + i0 + w) << 6) + lane] = v / s;
  }
}

extern "C" void kernel_launch(void* const* d_in, const int* in_sizes, int n_in,
                              void* d_out, int out_size, void* d_ws, size_t ws_size,
                              hipStream_t stream) {
  const float* x = (const float*)d_in[0];
  const float* a = (const float*)d_in[1];
  float* out = (float*)d_out;
  pairsim_kernel<<<NN * (VV / IB), 512, 0, stream>>>(x, a, out);
}